// Round 4
// baseline (139.776 us; speedup 1.0000x reference)
//
#include <hip/hip_runtime.h>

// StericClashConstraint: N=16384 pts [N,3] fp32.
// out[0..3N-1] = pos passthrough; out[3N] = mean(max(1-dist,0), diag=0) * 0.02
//
// Round 10: fix R9's stall disaster. R9 counters: VALU busy-time 7.3us (pruning
// worked) but wall 55.6us, avg block lifetime ~13us for ~2k cycles of math.
// Cause: j-reads were a serial s_load chain (scalar loads complete OUT of order
// -> compiler drains lgkmcnt(0) per batch -> prefetch dead), plus a
// lastz->binStart load chain in every block's prologue.
// Fixes:
//  (a) scan_kernel precomputes jend[g] for all 32 groups (binary search in the
//      LDS scan it already has). Pair prologue = ONE scalar load.
//  (b) Each pair block stages its j-window (<=256 float4) into LDS with one
//      coalesced vector load, then the inner loop reads wave-uniform
//      ds_read_b128 (broadcast, conflict-free, IN-ORDER completion -> compiler
//      emits counted lgkmcnt and pipelines). Sentinel pad kills tail code.
//  (c) i-fragment loads issued before staging to overlap latency.
// Math per included pair is bit-identical to R8/R9 (which passed absmax=0).
// Pruning guarantee unchanged: excluded pairs have dz >= 9/8 - eps > 1 -> 0.

constexpr int   N     = 16384;
constexpr int   BLOCK = 256;            // 4 waves
constexpr int   GSZ   = 512;            // i-group size
constexpr int   IPT   = GSZ / BLOCK;    // 2 i's per thread
constexpr int   NG    = N / GSZ;        // 32 i-groups
constexpr int   F     = 64;             // j-segments per group
constexpr int   NB    = NG * F;         // 2048 blocks = 8/CU
constexpr int   QB    = 4;              // columns per unrolled chunk
constexpr int   NBINS = 512;            // z-bins, width 1/8, covering [-32,32)
constexpr float BINW_INV = 8.0f;
constexpr int   MARGIN = 10;            // bin_j >= bin_last+10 => dz > 1 guaranteed
constexpr int   SEGMAX = 256;           // worst-case columns per block (jlen<=N)

__device__ __forceinline__ int zcell(float z) {
    int c = (int)floorf(z * BINW_INV) + NBINS / 2;
    return min(max(c, 0), NBINS - 1);
}

// ---- k1: passthrough + z-histogram -----------------------------------------
__global__ void prep_kernel(const float* __restrict__ pos, float* __restrict__ out,
                            unsigned int* __restrict__ hist) {
    const int t = blockIdx.x * blockDim.x + threadIdx.x;   // 0..16383
    if (t < (N * 3) / 4) {
        reinterpret_cast<float4*>(out)[t] = reinterpret_cast<const float4*>(pos)[t];
    }
    const float z = pos[3 * t + 2];
    atomicAdd(&hist[zcell(z)], 1u);
}

// ---- k2: scan + per-group j-window ends ------------------------------------
__global__ void scan_kernel(const unsigned int* __restrict__ hist,
                            unsigned int* __restrict__ cursor,
                            int* __restrict__ jendArr) {
    __shared__ int sm[NBINS];
    const int t = threadIdx.x;
    const int v = (int)hist[t];
    sm[t] = v;
    __syncthreads();
    for (int off = 1; off < NBINS; off <<= 1) {
        const int a = (t >= off) ? sm[t - off] : 0;
        __syncthreads();
        sm[t] += a;                       // sm becomes INCLUSIVE scan
        __syncthreads();
    }
    cursor[t] = (unsigned int)(sm[t] - v);   // exclusive start of bin t
    if (t < NG) {
        // bin of the last sorted point of group t: smallest c with incl[c] >= p+1
        const int p = (t + 1) * GSZ - 1;
        int lo = 0, hi = NBINS - 1;
        while (lo < hi) {
            const int mid = (lo + hi) >> 1;
            if (sm[mid] >= p + 1) hi = mid; else lo = mid + 1;
        }
        const int jidx = lo + MARGIN;
        jendArr[t] = (jidx >= NBINS) ? N : sm[jidx - 1];   // excl[jidx]
    }
}

// ---- k3: scatter into z-sorted {x,y,z,|p|^2} array -------------------------
__global__ void scatter_kernel(const float* __restrict__ pos,
                               unsigned int* __restrict__ cursor,
                               float4* __restrict__ jt4s) {
    const int t = blockIdx.x * blockDim.x + threadIdx.x;   // 0..16383
    const float x = pos[3 * t], y = pos[3 * t + 1], z = pos[3 * t + 2];
    const unsigned int dst = atomicAdd(&cursor[zcell(z)], 1u);
    jt4s[dst] = make_float4(x, y, z, fmaf(x, x, fmaf(y, y, z * z)));
}

// ---- k4: pruned pair sweep, j-window staged in LDS -------------------------
template <bool MASKED>
__device__ __forceinline__ float cols(const float4* __restrict__ jsm,
                                      int len, int j0, int i0,
                                      const float (&xi2)[IPT], const float (&yi2)[IPT],
                                      const float (&zi2)[IPT], const float (&sqi)[IPT]) {
    float s = 0.0f;
    for (int c = 0; c < len; c += QB) {            // sentinel pad covers overrun
        #pragma unroll
        for (int u = 0; u < QB; ++u) {
            const float4 pj = jsm[c + u];          // uniform addr -> broadcast
            const int jq = j0 + c + u;
            #pragma unroll
            for (int k = 0; k < IPT; ++k) {
                float d = fmaf(xi2[k], pj.x, pj.w);
                d = fmaf(yi2[k], pj.y, d);
                d = fmaf(zi2[k], pj.z, d);                     // sq_j - 2*dot
                const float d2 = fmaxf(d + sqi[k], 0.0f);      // + sq_i, clamp
                float w = 1.0f - __builtin_amdgcn_sqrtf(d2);   // 1 - dist
                w = fmaxf(w, 0.0f);                            // clamp(min=0)
                if (MASKED) w = (jq > i0 + k * BLOCK) ? w : 0.0f;   // j>i only
                s += w;
            }
        }
    }
    return s;
}

__global__ void __launch_bounds__(BLOCK, 8)
pair_kernel(const float4* __restrict__ jt4s, const int* __restrict__ jendArr,
            float* __restrict__ out, float* __restrict__ acc,
            unsigned int* __restrict__ cnt) {
    __shared__ float4 jsm[SEGMAX + QB];
    __shared__ float wsum[BLOCK / 64];
    const int b = blockIdx.x;
    const int t = threadIdx.x;
    const int g = b >> 6, f = b & (F - 1);
    const int gstart = g * GSZ;
    const int i0 = gstart + t;

    // issue i-fragment loads first (overlap with everything below)
    const float4 w0 = jt4s[i0];
    const float4 w1 = jt4s[i0 + BLOCK];

    const int jend = jendArr[g];                       // one scalar load
    const int jbeg = gstart + 1;
    const int jlen = jend - jbeg;
    const int seg  = (((jlen + F - 1) / F) + QB - 1) & ~(QB - 1);  // QB-aligned
    const int j0   = jbeg + f * seg;
    const int len  = min(seg, jend - j0);              // may be <= 0 (tail blocks)

    // stage j-window into LDS: one coalesced load + sentinel pad (no tail code)
    if (t < QB) jsm[max(len, 0) + t] = make_float4(0.0f, 0.0f, 1.0e6f, 4.0e12f);
    if (t < len) jsm[t] = jt4s[j0 + t];
    __syncthreads();

    float s = 0.0f;
    if (len > 0) {
        float xi2[IPT], yi2[IPT], zi2[IPT], sqi[IPT];
        xi2[0] = -2.0f * w0.x; yi2[0] = -2.0f * w0.y; zi2[0] = -2.0f * w0.z; sqi[0] = w0.w;
        xi2[1] = -2.0f * w1.x; yi2[1] = -2.0f * w1.y; zi2[1] = -2.0f * w1.z; sqi[1] = w1.w;
        if (j0 < gstart + GSZ)   // segment overlaps own group: need j>i mask
            s = cols<true >(jsm, len, j0, i0, xi2, yi2, zi2, sqi);
        else
            s = cols<false>(jsm, len, j0, i0, xi2, yi2, zi2, sqi);
    }

    // reduce: wave shuffle -> LDS -> one atomic per block
    for (int off = 32; off > 0; off >>= 1) s += __shfl_down(s, off);
    if ((t & 63) == 0) wsum[t >> 6] = s;
    __syncthreads();
    if (t == 0) {
        float bs = 0.0f;
        #pragma unroll
        for (int w = 0; w < BLOCK / 64; ++w) bs += wsum[w];
        atomicAdd(acc, bs);
        __threadfence();
        const unsigned int done = atomicAdd(cnt, 1u);
        if (done == (unsigned int)(NB - 1)) {          // last block finalizes
            __threadfence();
            const float total = atomicAdd(acc, 0.0f);  // device-coherent read
            const double mean = 2.0 * (double)total / ((double)N * (double)N);
            out[(size_t)N * 3] = (float)(mean * 0.02);
        }
    }
}

extern "C" void kernel_launch(void* const* d_in, const int* in_sizes, int n_in,
                              void* d_out, int out_size, void* d_ws, size_t ws_size,
                              hipStream_t stream) {
    const float* pos = (const float*)d_in[0];
    float* out = (float*)d_out;
    // ws layout:
    //   0:    acc (float)        4: cnt (uint)
    //   16:   hist[512]   (2048 B)           <- zeroed by memset
    //   2064: jend[32]    (128 B)
    //   4112: cursor[512] (2048 B)
    //   8192: jt4s[N x float4]  (256 KiB)
    float*        acc      = (float*)d_ws;
    unsigned int* cnt      = (unsigned int*)d_ws + 1;
    unsigned int* hist     = (unsigned int*)((char*)d_ws + 16);
    int*          jendArr  = (int*)((char*)d_ws + 2064);
    unsigned int* cursor   = (unsigned int*)((char*)d_ws + 4112);
    float4*       jt4s     = (float4*)((char*)d_ws + 8192);

    hipMemsetAsync(d_ws, 0, 2064, stream);   // acc, cnt, hist = 0

    prep_kernel   <<<N / 256, 256, 0, stream>>>(pos, out, hist);
    scan_kernel   <<<1, NBINS, 0, stream>>>(hist, cursor, jendArr);
    scatter_kernel<<<N / 256, 256, 0, stream>>>(pos, cursor, jt4s);
    pair_kernel   <<<NB, BLOCK, 0, stream>>>(jt4s, jendArr, out, acc, cnt);
}

// Round 5
// 91.854 us; speedup vs baseline: 1.5217x; 1.5217x over previous
//
#include <hip/hip_runtime.h>

// StericClashConstraint: N=16384 pts [N,3] fp32.
// out[0..3N-1] = pos passthrough; out[3N] = mean(max(1-dist,0), diag=0) * 0.02
//
// Round 11: WORKGROUP-COUNT-BOUND fix. R9/R10 post-mortem: every 2048-block
// pair kernel walls at ~55us regardless of inner loop (R9 55.6 scalar-chain,
// R10 54.6 LDS-staged), with only ~7us of VALU busy-time and 20% occupancy
// (CUs starved - waves retire faster than WGs arrive). ~26ns serialized cost
// per WG (dispatch/teardown + 2 same-address atomics each). Fix:
//  (a) pair grid 2048 -> 256 blocks (F=8, 1/CU). Per-block work x8 (seg <=
//      ~272 cols, staged in LDS chunks of 288), WG + atomic count /8.
//      Math is issue-bound with 8-way ILP -> 4 waves/CU is enough.
//  (b) dispatches 5 -> 4: no memset. prep zeroes acc/cnt (stream-ordered,
//      proven in R8); histogram via per-block PARTIALS (LDS-zeroed, no global
//      pre-zero needed); scan sums partials. All ws state fully rewritten
//      every replay -> graph-replay-safe.
// Per-pair math bit-identical to R8/R9/R10 (absmax=0.0). Pruning guarantee
// unchanged: excluded pairs have dz >= 9/8 - eps > 1 -> contribution exactly 0.

constexpr int   N     = 16384;
constexpr int   BLOCK = 256;            // 4 waves
constexpr int   GSZ   = 512;            // i-group size
constexpr int   IPT   = GSZ / BLOCK;    // 2 i's per thread
constexpr int   NG    = N / GSZ;        // 32 i-groups
constexpr int   F     = 8;              // j-segments per group
constexpr int   NB    = NG * F;         // 256 blocks = 1/CU
constexpr int   QB    = 4;              // columns per unrolled chunk
constexpr int   NBINS = 512;            // z-bins, width 1/8, covering [-32,32)
constexpr float BINW_INV = 8.0f;
constexpr int   MARGIN = 10;            // bin_j >= bin_last+10 => dz > 1 guaranteed
constexpr int   CH    = 288;            // columns staged per LDS chunk
constexpr int   NPB   = N / BLOCK;      // 64 prep blocks

__device__ __forceinline__ int zcell(float z) {
    int c = (int)floorf(z * BINW_INV) + NBINS / 2;
    return min(max(c, 0), NBINS - 1);
}

// ---- k1: passthrough + per-block partial histogram + acc/cnt zero ----------
__global__ void prep_kernel(const float* __restrict__ pos, float* __restrict__ out,
                            unsigned int* __restrict__ histPart,
                            float* __restrict__ acc, unsigned int* __restrict__ cnt) {
    __shared__ unsigned int lh[NBINS];
    const int b = blockIdx.x, t = threadIdx.x;
    const int gt = b * BLOCK + t;                     // 0..16383
    lh[t] = 0u; lh[t + BLOCK] = 0u;
    if (gt == 0) { *acc = 0.0f; *cnt = 0u; }          // replaces memset
    __syncthreads();
    if (gt < (N * 3) / 4) {
        reinterpret_cast<float4*>(out)[gt] = reinterpret_cast<const float4*>(pos)[gt];
    }
    const float z = pos[3 * gt + 2];
    atomicAdd(&lh[zcell(z)], 1u);                     // LDS atomic
    __syncthreads();
    histPart[b * NBINS + t]         = lh[t];
    histPart[b * NBINS + t + BLOCK] = lh[t + BLOCK];
}

// ---- k2: sum partials + scan + cursor + per-group j-window ends ------------
__global__ void scan_kernel(const unsigned int* __restrict__ histPart,
                            unsigned int* __restrict__ cursor,
                            int* __restrict__ jendArr) {
    __shared__ int sm[NBINS];
    const int t = threadIdx.x;                        // 512 threads
    int v = 0;
    for (int b = 0; b < NPB; ++b) v += (int)histPart[b * NBINS + t];
    sm[t] = v;
    __syncthreads();
    for (int off = 1; off < NBINS; off <<= 1) {
        const int a = (t >= off) ? sm[t - off] : 0;
        __syncthreads();
        sm[t] += a;                                   // sm becomes INCLUSIVE scan
        __syncthreads();
    }
    cursor[t] = (unsigned int)(sm[t] - v);            // exclusive start of bin t
    if (t < NG) {
        // bin of last sorted point of group t: smallest c with incl[c] >= p+1
        const int p = (t + 1) * GSZ - 1;
        int lo = 0, hi = NBINS - 1;
        while (lo < hi) {
            const int mid = (lo + hi) >> 1;
            if (sm[mid] >= p + 1) hi = mid; else lo = mid + 1;
        }
        const int jidx = lo + MARGIN;
        jendArr[t] = (jidx >= NBINS) ? N : sm[jidx - 1];   // excl[jidx]
    }
}

// ---- k3: scatter into z-sorted {x,y,z,|p|^2} array -------------------------
__global__ void scatter_kernel(const float* __restrict__ pos,
                               unsigned int* __restrict__ cursor,
                               float4* __restrict__ jt4s) {
    const int t = blockIdx.x * blockDim.x + threadIdx.x;   // 0..16383
    const float x = pos[3 * t], y = pos[3 * t + 1], z = pos[3 * t + 2];
    const unsigned int dst = atomicAdd(&cursor[zcell(z)], 1u);
    jt4s[dst] = make_float4(x, y, z, fmaf(x, x, fmaf(y, y, z * z)));
}

// ---- k4: pruned pair sweep, chunked LDS staging, 256 fat blocks ------------
template <bool MASKED>
__device__ __forceinline__ float cols(const float4* __restrict__ jsm,
                                      int clen, int jbase, int i0,
                                      const float (&xi2)[IPT], const float (&yi2)[IPT],
                                      const float (&zi2)[IPT], const float (&sqi)[IPT]) {
    float s = 0.0f;
    for (int c = 0; c < clen; c += QB) {              // sentinel pad covers overrun
        #pragma unroll
        for (int u = 0; u < QB; ++u) {
            const float4 pj = jsm[c + u];             // uniform addr -> broadcast
            const int jq = jbase + c + u;
            #pragma unroll
            for (int k = 0; k < IPT; ++k) {
                float d = fmaf(xi2[k], pj.x, pj.w);
                d = fmaf(yi2[k], pj.y, d);
                d = fmaf(zi2[k], pj.z, d);                     // sq_j - 2*dot
                const float d2 = fmaxf(d + sqi[k], 0.0f);      // + sq_i, clamp
                float w = 1.0f - __builtin_amdgcn_sqrtf(d2);   // 1 - dist
                w = fmaxf(w, 0.0f);                            // clamp(min=0)
                if (MASKED) w = (jq > i0 + k * BLOCK) ? w : 0.0f;   // j>i only
                s += w;
            }
        }
    }
    return s;
}

__global__ void __launch_bounds__(BLOCK)
pair_kernel(const float4* __restrict__ jt4s, const int* __restrict__ jendArr,
            float* __restrict__ out, float* __restrict__ acc,
            unsigned int* __restrict__ cnt) {
    __shared__ float4 jsm[CH + QB];
    __shared__ float wsum[BLOCK / 64];
    const int b = blockIdx.x;
    const int t = threadIdx.x;
    const int g = b >> 3, f = b & (F - 1);
    const int gstart = g * GSZ;
    const int i0 = gstart + t;

    // issue i-fragment loads first (overlap with jend load + param math)
    const float4 w0 = jt4s[i0];
    const float4 w1 = jt4s[i0 + BLOCK];

    const int jend = jendArr[g];                       // one scalar load
    const int jbeg = gstart + 1;
    const int jlen = jend - jbeg;                      // >= GSZ-1 always
    const int seg  = (((jlen + F - 1) / F) + QB - 1) & ~(QB - 1);  // QB-aligned
    const int j0   = jbeg + f * seg;
    const int len  = min(seg, jend - j0);              // > 0 for all f (jlen>=511)

    float xi2[IPT], yi2[IPT], zi2[IPT], sqi[IPT];
    xi2[0] = -2.0f * w0.x; yi2[0] = -2.0f * w0.y; zi2[0] = -2.0f * w0.z; sqi[0] = w0.w;
    xi2[1] = -2.0f * w1.x; yi2[1] = -2.0f * w1.y; zi2[1] = -2.0f * w1.z; sqi[1] = w1.w;

    float s = 0.0f;
    for (int cs = 0; cs < len; cs += CH) {             // 1 chunk for this data
        const int clen = min(CH, len - cs);
        // cooperative stage (two guarded rounds cover CH=288 > BLOCK)
        if (t < clen)         jsm[t]         = jt4s[j0 + cs + t];
        if (t + BLOCK < clen) jsm[t + BLOCK] = jt4s[j0 + cs + t + BLOCK];
        if (t < QB) jsm[clen + t] = make_float4(0.0f, 0.0f, 1.0e6f, 4.0e12f);
        __syncthreads();
        if (j0 + cs < gstart + GSZ)    // chunk may overlap own group: j>i mask
            s += cols<true >(jsm, clen, j0 + cs, i0, xi2, yi2, zi2, sqi);
        else
            s += cols<false>(jsm, clen, j0 + cs, i0, xi2, yi2, zi2, sqi);
        __syncthreads();               // before next chunk overwrites jsm
    }

    // reduce: wave shuffle -> LDS -> one atomic per block
    for (int off = 32; off > 0; off >>= 1) s += __shfl_down(s, off);
    if ((t & 63) == 0) wsum[t >> 6] = s;
    __syncthreads();
    if (t == 0) {
        float bs = 0.0f;
        #pragma unroll
        for (int w = 0; w < BLOCK / 64; ++w) bs += wsum[w];
        atomicAdd(acc, bs);
        __threadfence();
        const unsigned int done = atomicAdd(cnt, 1u);
        if (done == (unsigned int)(NB - 1)) {          // last block finalizes
            __threadfence();
            const float total = atomicAdd(acc, 0.0f);  // device-coherent read
            const double mean = 2.0 * (double)total / ((double)N * (double)N);
            out[(size_t)N * 3] = (float)(mean * 0.02);
        }
    }
}

extern "C" void kernel_launch(void* const* d_in, const int* in_sizes, int n_in,
                              void* d_out, int out_size, void* d_ws, size_t ws_size,
                              hipStream_t stream) {
    const float* pos = (const float*)d_in[0];
    float* out = (float*)d_out;
    // ws layout:
    //   0:      acc (float)      4: cnt (uint)
    //   256:    jend[32]            (128 B)
    //   512:    cursor[512]         (2048 B)
    //   4096:   histPart[64][512]   (128 KiB)
    //   135168: jt4s[N x float4]    (256 KiB)
    float*        acc      = (float*)d_ws;
    unsigned int* cnt      = (unsigned int*)d_ws + 1;
    int*          jendArr  = (int*)((char*)d_ws + 256);
    unsigned int* cursor   = (unsigned int*)((char*)d_ws + 512);
    unsigned int* histPart = (unsigned int*)((char*)d_ws + 4096);
    float4*       jt4s     = (float4*)((char*)d_ws + 135168);

    prep_kernel   <<<NPB, BLOCK, 0, stream>>>(pos, out, histPart, acc, cnt);
    scan_kernel   <<<1, NBINS, 0, stream>>>(histPart, cursor, jendArr);
    scatter_kernel<<<NPB, BLOCK, 0, stream>>>(pos, cursor, jt4s);
    pair_kernel   <<<NB, BLOCK, 0, stream>>>(jt4s, jendArr, out, acc, cnt);
}